// Round 10
// baseline (77897.412 us; speedup 1.0000x reference)
//
#include <hip/hip_runtime.h>
#include <math.h>

#define HDIM 1024
#define NTAG 256
#define BSZ 128
#define TLEN 50
#define G3 3072
#define NBLK 512
#define NGRP 16

typedef unsigned long long u64;

// ---- static f32 pool, recurrent tensors transposed [k][b] ----
constexpr u64 GX_F  = (u64)TLEN*G3*BSZ;     // gx [t][n][b]
constexpr u64 SEQ_F = (u64)TLEN*HDIM*BSZ;   // [t][k][b]
constexpr u64 HST_F = (u64)HDIM*BSZ;        // h [k][b]
constexpr u64 F_GX  = 0;
constexpr u64 F_OF0 = F_GX + GX_F;
constexpr u64 F_OB0 = F_OF0 + SEQ_F;
constexpr u64 F_ENC = F_OB0 + SEQ_F;
constexpr u64 F_T0  = F_ENC + SEQ_F;
constexpr u64 F_T1  = F_T0 + HST_F;
constexpr u64 F_H0F = F_T1 + HST_F;
constexpr u64 F_H0B = F_H0F + HST_F;
constexpr u64 F_D0A = F_H0B + HST_F;
constexpr u64 F_D0B = F_D0A + HST_F;
constexpr u64 F_D1A = F_D0B + HST_F;
constexpr u64 F_D1B = F_D1A + HST_F;
constexpr u64 F_CTX = F_D1B + HST_F;
constexpr u64 F_CC  = F_CTX + HST_F;
constexpr u64 F_LG  = F_CC + HST_F;                 // logits [v][b]
constexpr u64 F_QP  = F_LG + (u64)NTAG*BSZ;         // 8 x TLEN x BSZ score partials
constexpr u64 F_A   = F_QP + (u64)8*TLEN*BSZ;       // attn weights [tp][b]
constexpr u64 F_NLL = F_A + (u64)TLEN*BSZ;
constexpr u64 POOL_F= F_NLL + (u64)TLEN*BSZ;

__device__ __align__(256) float g_pool[POOL_F];
__device__ unsigned g_grp[NGRP*32];
__device__ unsigned g_root;
__device__ unsigned g_gen;

__device__ __forceinline__ float sigmf(float x){ return 1.f/(1.f+__expf(-x)); }

// two-level tree barrier: 16 padded group counters + root; all 512 blocks co-resident (2/CU)
__device__ __forceinline__ void grid_sync(){
  __syncthreads();
  if (threadIdx.x == 0){
    __threadfence();
    const int g = blockIdx.x & (NGRP-1);
    unsigned gen = __hip_atomic_load(&g_gen, __ATOMIC_RELAXED, __HIP_MEMORY_SCOPE_AGENT);
    unsigned old = __hip_atomic_fetch_add(&g_grp[g*32], 1u, __ATOMIC_ACQ_REL, __HIP_MEMORY_SCOPE_AGENT);
    if (old == (NBLK/NGRP)-1){
      unsigned ro = __hip_atomic_fetch_add(&g_root, 1u, __ATOMIC_ACQ_REL, __HIP_MEMORY_SCOPE_AGENT);
      if (ro == NGRP-1){
        __hip_atomic_store(&g_root, 0u, __ATOMIC_RELAXED, __HIP_MEMORY_SCOPE_AGENT);
        #pragma unroll
        for (int i=0;i<NGRP;++i)
          __hip_atomic_store(&g_grp[i*32], 0u, __ATOMIC_RELAXED, __HIP_MEMORY_SCOPE_AGENT);
        __hip_atomic_fetch_add(&g_gen, 1u, __ATOMIC_ACQ_REL, __HIP_MEMORY_SCOPE_AGENT);
      } else {
        while (__hip_atomic_load(&g_gen, __ATOMIC_ACQUIRE, __HIP_MEMORY_SCOPE_AGENT) == gen)
          __builtin_amdgcn_s_sleep(2);
      }
    } else {
      while (__hip_atomic_load(&g_gen, __ATOMIC_ACQUIRE, __HIP_MEMORY_SCOPE_AGENT) == gen)
        __builtin_amdgcn_s_sleep(2);
    }
    __threadfence();
  }
  __syncthreads();
}

// Full-K partial GEMM: R rows, k split across 4 waves (KPW each), A [k][b] from global,
// 8-deep load prefetch. W either LDS-resident (wl[k*R+r]) or global rows (uniform->SGPR).
template<int R, int KPW, bool WLDS>
__device__ __forceinline__ void gfk(const float* __restrict__ wl,
                                    const float* __restrict__ Wg, int ldw,
                                    const int* rows,
                                    const float* __restrict__ aT0,
                                    const float* __restrict__ aT1, int K0,
                                    float acc[R][2], int tid)
{
  const int w = tid>>6, l2 = (tid&63)*2;
  #pragma unroll
  for (int r=0;r<R;++r){ acc[r][0]=0.f; acc[r][1]=0.f; }
  const int k0 = w*KPW;
  const float* ap = ((k0 < K0)? (aT0 + (u64)k0*BSZ) : (aT1 + (u64)(k0-K0)*BSZ)) + l2;
  const float* wg[R];
  if constexpr (!WLDS){
    #pragma unroll
    for (int r=0;r<R;++r) wg[r] = Wg + (u64)rows[r]*ldw + k0;
  }
  const float* wp = WLDS ? (wl + (u64)k0*R) : nullptr;
  for (int kb=0; kb<KPW; kb+=8){
    float2 a[8];
    #pragma unroll
    for (int u=0;u<8;++u) a[u] = *(const float2*)(ap + (u64)(kb+u)*BSZ);
    #pragma unroll
    for (int u=0;u<8;++u){
      #pragma unroll
      for (int r=0;r<R;++r){
        float wv;
        if constexpr (WLDS) wv = wp[(u64)(kb+u)*R + r];
        else                wv = wg[r][kb+u];
        acc[r][0] += wv*a[u].x; acc[r][1] += wv*a[u].y;
      }
    }
  }
}

// cross-wave reduce buffer: red[(w*R+r)*128 + b]
template<int R>
__device__ __forceinline__ void reduceR(const float acc[R][2], float* red, int tid){
  const int w = tid>>6, l2 = (tid&63)*2;
  __syncthreads();
  #pragma unroll
  for (int r=0;r<R;++r){
    red[(u64)(w*R+r)*128 + l2]   = acc[r][0];
    red[(u64)(w*R+r)*128 + l2+1] = acc[r][1];
  }
  __syncthreads();
}

#define AM_ENC 0
#define AM_DEC 1
#define AM_CAT 2

// gx[(t*G3+n)*BSZ+b] = A[t,b,:] @ W[n,:]^T + bias[n]  (unchanged)
template<int AMODE>
__global__ __launch_bounds__(256)
void gemm_gx(const float* __restrict__ embed,
             u64 a1_f, u64 a2_f,
             const int* __restrict__ ids,
             const float* __restrict__ W,
             const float* __restrict__ bias,
             u64 c_f, int K)
{
  constexpr int TM=128, TN=64, TK=32;
  __shared__ float As[TK][TM+4];
  __shared__ float Ws[TK][TN+4];
  __shared__ int rowid[TM];
  const int t = blockIdx.x;
  const int n0 = blockIdx.y*TN;
  const int tid = threadIdx.x;

  if (AMODE != AM_CAT){
    for (int r=tid; r<TM; r+=256)
      rowid[r] = (AMODE==AM_ENC) ? ids[r*TLEN+t] : ((t==0)?1:ids[r*TLEN+t-1]);
    __syncthreads();
  }

  const int tm = tid>>4, tn = tid&15;
  float acc[8][4];
  #pragma unroll
  for (int i=0;i<8;i++){ acc[i][0]=0.f;acc[i][1]=0.f;acc[i][2]=0.f;acc[i][3]=0.f; }

  for (int k0=0;k0<K;k0+=TK){
    if (AMODE==AM_CAT){
      const int kk = tid>>3, q = tid&7;
      const int kg = k0 + kk;
      const float* src = g_pool + ((kg<HDIM)? (a1_f + ((u64)t*HDIM + kg)*BSZ)
                                            : (a2_f + ((u64)t*HDIM + (kg-HDIM))*BSZ)) + q*16;
      float* d = &As[kk][q*16];
      float4 v0=*(const float4*)(src+0), v1=*(const float4*)(src+4);
      float4 v2=*(const float4*)(src+8), v3=*(const float4*)(src+12);
      *(float4*)(d+0)=v0; *(float4*)(d+4)=v1; *(float4*)(d+8)=v2; *(float4*)(d+12)=v3;
    } else {
      #pragma unroll
      for (int l=tid; l<TM*TK; l+=256){
        int r=l>>5, k=l&31;
        As[k][r] = embed[(u64)rowid[r]*HDIM + k0 + k];
      }
    }
    #pragma unroll
    for (int l=tid; l<TN*TK; l+=256){
      int n=l>>5, k=l&31;
      Ws[k][n] = W[(u64)(n0+n)*K + k0 + k];
    }
    __syncthreads();
    #pragma unroll 8
    for (int kk=0;kk<TK;kk++){
      float4 a0 = *(const float4*)&As[kk][tm*8];
      float4 a1 = *(const float4*)&As[kk][tm*8+4];
      float4 w  = *(const float4*)&Ws[kk][tn*4];
      float av[8]={a0.x,a0.y,a0.z,a0.w,a1.x,a1.y,a1.z,a1.w};
      float wv[4]={w.x,w.y,w.z,w.w};
      #pragma unroll
      for (int i=0;i<8;i++){
        #pragma unroll
        for (int jj=0;jj<4;jj++) acc[i][jj] += av[i]*wv[jj];
      }
    }
    __syncthreads();
  }

  float bv[4];
  #pragma unroll
  for (int jj=0;jj<4;jj++) bv[jj] = bias[n0+tn*4+jj];
  float* C = g_pool + c_f;
  for (int half=0; half<2; ++half){
    if ((tn>>3)==half){
      #pragma unroll
      for (int i=0;i<8;i++)
        #pragma unroll
        for (int jj=0;jj<4;jj++)
          As[(tn&7)*4+jj][tm*8+i] = acc[i][jj]+bv[jj];
    }
    __syncthreads();
    {
      const int nn = tid>>3, q = tid&7;
      float* dst = C + ((u64)t*G3 + n0 + half*32 + nn)*BSZ + q*16;
      const float* srow = &As[nn][q*16];
      float4 v0=*(const float4*)(srow+0), v1=*(const float4*)(srow+4);
      float4 v2=*(const float4*)(srow+8), v3=*(const float4*)(srow+12);
      *(float4*)(dst+0)=v0; *(float4*)(dst+4)=v1; *(float4*)(dst+8)=v2; *(float4*)(dst+12)=v3;
    }
    __syncthreads();
  }
}

// persistent masked GRU scan: 512 blocks, 2 j-cols each, 1 barrier/step
template<bool BWD, bool ACCUM>
__global__ __launch_bounds__(256,2)
void scan_kernel(u64 gx_f, u64 p0_f, u64 p1_f,
                 const float* __restrict__ whh, const float* __restrict__ bhh,
                 const int* __restrict__ lengths, u64 out_f)
{
  __shared__ float wl[HDIM*6];       // 24 KB
  __shared__ float red[4*6*128];     // 12 KB
  const int bid = blockIdx.x, tid = threadIdx.x;
  const int j0 = bid*2;
  #pragma unroll
  for (int r=0;r<6;++r){
    const int row = (r>>1)*HDIM + j0 + (r&1);
    for (int k=tid;k<HDIM;k+=256) wl[k*6+r] = whh[(u64)row*HDIM + k];
  }
  __syncthreads();

  const int jj = tid>>7, bb = tid&127;
  const int jg = j0 + jj;
  const float b_r = bhh[jg], b_z = bhh[HDIM+jg], b_n = bhh[2*HDIM+jg];
  const int len = lengths[bb];

  for (int s=0; s<TLEN; ++s){
    const int t = BWD ? (TLEN-1-s) : s;
    const u64 rd = (s&1)? p0_f : p1_f;
    const u64 wr = (s&1)? p1_f : p0_f;
    float gh[3] = {0.f,0.f,0.f};
    if (s>0){
      float acc[6][2];
      gfk<6,256,true>(wl, nullptr, 0, nullptr, g_pool+rd, g_pool+rd, 1<<28, acc, tid);
      reduceR<6>(acc, red, tid);
      #pragma unroll
      for (int g=0;g<3;++g){
        float sum = red[(u64)(0*6+g*2+jj)*128+bb] + red[(u64)(1*6+g*2+jj)*128+bb];
        sum += red[(u64)(2*6+g*2+jj)*128+bb] + red[(u64)(3*6+g*2+jj)*128+bb];
        gh[g] = sum;
      }
    }
    const float* gxb = g_pool + gx_f + (u64)t*G3*BSZ;
    const bool m = (t < len);
    const float xr = gxb[(u64)jg*BSZ + bb];
    const float xz = gxb[(u64)(HDIM+jg)*BSZ + bb];
    const float xn = gxb[(u64)(2*HDIM+jg)*BSZ + bb];
    const float hp = (s>0)? g_pool[rd + (u64)jg*BSZ + bb] : 0.f;
    const float r = sigmf(xr + gh[0] + b_r);
    const float z = sigmf(xz + gh[1] + b_z);
    const float n = tanhf(xn + r*(gh[2] + b_n));
    const float hv = (1.f-z)*n + z*hp;
    g_pool[wr + (u64)jg*BSZ + bb] = m ? hv : hp;
    const u64 oidx = out_f + ((u64)t*HDIM + jg)*BSZ + bb;
    if (ACCUM){ if (m) g_pool[oidx] += hv; }
    else g_pool[oidx] = m ? hv : 0.f;
    grid_sync();
  }
}

// persistent decoder: 512 blocks, 7 grid barriers per step
__global__ __launch_bounds__(256,2)
void decoder_kernel(const float* __restrict__ whh0, const float* __restrict__ bhh0,
                    const float* __restrict__ wih1, const float* __restrict__ bih1,
                    const float* __restrict__ whh1, const float* __restrict__ bhh1,
                    const float* __restrict__ cw, const float* __restrict__ cb,
                    const float* __restrict__ ow, const float* __restrict__ ob,
                    const int* __restrict__ tag_ids, const int* __restrict__ lengths,
                    float* __restrict__ dout)
{
  __shared__ float wl0[HDIM*6];      // whh0, 24 KB
  __shared__ float wl2[HDIM*6];      // whh1, 24 KB
  __shared__ float red[4*6*128];     // 12 KB
  const int bid = blockIdx.x, tid = threadIdx.x;
  const int j0 = bid*2;
  int rows6[6];
  #pragma unroll
  for (int r=0;r<6;++r) rows6[r] = (r>>1)*HDIM + j0 + (r&1);
  #pragma unroll
  for (int r=0;r<6;++r){
    const int row = rows6[r];
    for (int k=tid;k<HDIM;k+=256){
      wl0[k*6+r] = whh0[(u64)row*HDIM + k];
      wl2[k*6+r] = whh1[(u64)row*HDIM + k];
    }
  }
  __syncthreads();

  const int jj = tid>>7, bb = tid&127;
  const int jg = j0 + jj;

  for (int t=0; t<TLEN; ++t){
    const u64 h0c = (t==0)? F_H0F : ((t&1)? F_D0A : F_D0B);
    const u64 h0n = (t&1)? F_D0B : F_D0A;
    const u64 h1c = (t==0)? F_H0B : ((t&1)? F_D1A : F_D1B);
    const u64 h1n = (t&1)? F_D1B : F_D1A;

    // ---- P1: layer-0 GRU ----
    {
      float acc[6][2];
      gfk<6,256,true>(wl0, nullptr, 0, nullptr, g_pool+h0c, g_pool+h0c, 1<<28, acc, tid);
      reduceR<6>(acc, red, tid);
      float gh[3];
      #pragma unroll
      for (int g=0;g<3;++g){
        float sum = red[(u64)(0*6+g*2+jj)*128+bb] + red[(u64)(1*6+g*2+jj)*128+bb];
        sum += red[(u64)(2*6+g*2+jj)*128+bb] + red[(u64)(3*6+g*2+jj)*128+bb];
        gh[g] = sum;
      }
      const float* gxb = g_pool + F_GX + (u64)t*G3*BSZ;
      const float b_r=bhh0[jg], b_z=bhh0[HDIM+jg], b_n=bhh0[2*HDIM+jg];
      const float xr = gxb[(u64)jg*BSZ+bb], xz = gxb[(u64)(HDIM+jg)*BSZ+bb], xn = gxb[(u64)(2*HDIM+jg)*BSZ+bb];
      const float hp = g_pool[h0c + (u64)jg*BSZ + bb];
      const float r = sigmf(xr + gh[0] + b_r), z = sigmf(xz + gh[1] + b_z);
      const float n = tanhf(xn + r*(gh[2] + b_n));
      g_pool[h0n + (u64)jg*BSZ + bb] = (1.f-z)*n + z*hp;
    }
    grid_sync();   // b1

    // ---- P2: layer-1 GRU ----
    {
      float acc[6][2], aX[3], aH[3];
      gfk<6,256,false>(nullptr, wih1, HDIM, rows6, g_pool+h0n, g_pool+h0n, 1<<28, acc, tid);
      reduceR<6>(acc, red, tid);
      #pragma unroll
      for (int g=0;g<3;++g){
        float sum = red[(u64)(0*6+g*2+jj)*128+bb] + red[(u64)(1*6+g*2+jj)*128+bb];
        sum += red[(u64)(2*6+g*2+jj)*128+bb] + red[(u64)(3*6+g*2+jj)*128+bb];
        aX[g] = sum;
      }
      gfk<6,256,true>(wl2, nullptr, 0, nullptr, g_pool+h1c, g_pool+h1c, 1<<28, acc, tid);
      reduceR<6>(acc, red, tid);
      #pragma unroll
      for (int g=0;g<3;++g){
        float sum = red[(u64)(0*6+g*2+jj)*128+bb] + red[(u64)(1*6+g*2+jj)*128+bb];
        sum += red[(u64)(2*6+g*2+jj)*128+bb] + red[(u64)(3*6+g*2+jj)*128+bb];
        aH[g] = sum;
      }
      const float bxr=bih1[jg], bxz=bih1[HDIM+jg], bxn=bih1[2*HDIM+jg];
      const float bhr=bhh1[jg], bhz=bhh1[HDIM+jg], bhn=bhh1[2*HDIM+jg];
      const float hp = g_pool[h1c + (u64)jg*BSZ + bb];
      const float r = sigmf(aX[0]+bxr + aH[0]+bhr), z = sigmf(aX[1]+bxz + aH[1]+bhz);
      const float n = tanhf(aX[2]+bxn + r*(aH[2]+bhn));
      g_pool[h1n + (u64)jg*BSZ + bb] = (1.f-z)*n + z*hp;
    }
    grid_sync();   // b2

    // ---- P3: score partials (400 blocks x 128 k) ----
    if (bid < 400 && tid < 128){
      const int tp = bid>>3, kq = bid&7;
      const int b = tid;
      const float* hT = g_pool + h1n;
      const float* eT = g_pool + F_ENC + (u64)tp*HDIM*BSZ;
      const int kst = kq*128;
      float s0=0.f,s1=0.f,s2=0.f,s3=0.f;
      for (int k=kst;k<kst+128;k+=4){
        s0 += hT[(u64)k*BSZ+b]     * eT[(u64)k*BSZ+b];
        s1 += hT[(u64)(k+1)*BSZ+b] * eT[(u64)(k+1)*BSZ+b];
        s2 += hT[(u64)(k+2)*BSZ+b] * eT[(u64)(k+2)*BSZ+b];
        s3 += hT[(u64)(k+3)*BSZ+b] * eT[(u64)(k+3)*BSZ+b];
      }
      g_pool[F_QP + (u64)kq*TLEN*BSZ + (u64)tp*BSZ + b] = (s0+s1)+(s2+s3);
    }
    grid_sync();   // b3

    // ---- P4a: softmax over tp ----
    if (bid < BSZ && tid < 64){
      const int b = bid;
      float v = -1e30f;
      if (tid < TLEN){
        v = 0.f;
        #pragma unroll
        for (int q=0;q<8;++q) v += g_pool[F_QP + (u64)q*TLEN*BSZ + (u64)tid*BSZ + b];
      }
      float mx = v;
      #pragma unroll
      for (int o=32;o;o>>=1) mx = fmaxf(mx, __shfl_xor(mx,o));
      float e = (tid<TLEN)? __expf(v-mx) : 0.f;
      float sm = e;
      #pragma unroll
      for (int o=32;o;o>>=1) sm += __shfl_xor(sm,o);
      if (tid < TLEN) g_pool[F_A + (u64)tid*BSZ + b] = e/sm;
    }
    grid_sync();   // b4

    // ---- P4b: ctx[k][b] (512 blocks x 2 k) ----
    {
      const int k = bid*2 + (tid>>7), b = tid&127;
      float acc = 0.f;
      #pragma unroll 5
      for (int tp=0;tp<TLEN;++tp)
        acc += g_pool[F_A + (u64)tp*BSZ + b] * g_pool[F_ENC + ((u64)tp*HDIM + k)*BSZ + b];
      g_pool[F_CTX + (u64)k*BSZ + b] = acc;
    }
    grid_sync();   // b5

    // ---- P5: cc rows (512 blocks x 2 rows, K=2048) ----
    {
      int rows2[2] = { bid*2, bid*2+1 };
      float acc2[2][2];
      gfk<2,512,false>(nullptr, cw, 2*HDIM, rows2, g_pool+h1n, g_pool+F_CTX, 1024, acc2, tid);
      reduceR<2>(acc2, red, tid);
      const int n = bid*2 + jj;
      float s = cb[n];
      #pragma unroll
      for (int w2=0;w2<4;++w2) s += red[(u64)(w2*2+jj)*128 + bb];
      g_pool[F_CC + (u64)n*BSZ + bb] = tanhf(s);
    }
    grid_sync();   // b6

    // ---- P6: logits (256 blocks x 1 row, K=1024) ----
    if (bid < NTAG){
      int rows1[1] = { bid };
      float acc1[1][2];
      gfk<1,256,false>(nullptr, ow, HDIM, rows1, g_pool+F_CC, g_pool+F_CC, 1<<28, acc1, tid);
      reduceR<1>(acc1, red, tid);
      if (tid < 128){
        float lg = ob[bid];
        #pragma unroll
        for (int w2=0;w2<4;++w2) lg += red[(u64)w2*128 + tid];
        g_pool[F_LG + (u64)bid*BSZ + tid] = lg;
      }
    }
    grid_sync();   // b7

    // ---- P7: per-b softmax, write dout + nll ----
    if (bid < BSZ){
      float* lgs = red;
      float* rp  = red + 256;
      const int b = bid, v = tid;
      const float lg = g_pool[F_LG + (u64)v*BSZ + b];
      lgs[v] = lg; rp[v] = lg;
      __syncthreads();
      for (int o=128;o;o>>=1){ if (tid<o) rp[tid]=fmaxf(rp[tid],rp[tid+o]); __syncthreads(); }
      const float mx = rp[0];
      __syncthreads();
      rp[tid] = __expf(lg-mx);
      __syncthreads();
      for (int o=128;o;o>>=1){ if (tid<o) rp[tid]+=rp[tid+o]; __syncthreads(); }
      const float lse = mx + __logf(rp[0]);
      dout[((u64)b*TLEN + t)*NTAG + v] = lg;
      if (tid==0){
        const int tag = tag_ids[b*TLEN + t];
        g_pool[F_NLL + (u64)t*BSZ + b] = lse - lgs[tag];
      }
    }
    // no trailing barrier: next-step P1 touches disjoint buffers; b1 orders reuse
  }
  grid_sync();
  // ---- loss ----
  if (bid == 0){
    float* rp = red;
    float ssum = 0.f;
    for (int i=tid; i<TLEN*BSZ; i+=256){
      const int tt = i>>7, b = i&127;
      if (tt < lengths[b]) ssum += g_pool[F_NLL + i];
    }
    rp[tid] = ssum; __syncthreads();
    for (int o=128;o;o>>=1){ if (tid<o) rp[tid]+=rp[tid+o]; __syncthreads(); }
    if (tid==0){
      int den=0;
      for (int b=0;b<BSZ;b++) den += lengths[b];
      dout[(u64)BSZ*TLEN*NTAG] = rp[0]/(float)den;
    }
  }
}

extern "C" void kernel_launch(void* const* d_in, const int* in_sizes, int n_in,
                              void* d_out, int out_size, void* d_ws, size_t ws_size,
                              hipStream_t stream)
{
  const float* enc_embed = (const float*)d_in[0];
  const float* e0_wih = (const float*)d_in[1];
  const float* e0_whh = (const float*)d_in[2];
  const float* e0_bih = (const float*)d_in[3];
  const float* e0_bhh = (const float*)d_in[4];
  const float* e1_wih = (const float*)d_in[5];
  const float* e1_whh = (const float*)d_in[6];
  const float* e1_bih = (const float*)d_in[7];
  const float* e1_bhh = (const float*)d_in[8];
  const float* dec_embed = (const float*)d_in[9];
  const float* d_wih = (const float*)d_in[10];
  const float* d_whh = (const float*)d_in[11];
  const float* d_bih = (const float*)d_in[12];
  const float* d_bhh = (const float*)d_in[13];
  const float* concat_w = (const float*)d_in[14];
  const float* concat_b = (const float*)d_in[15];
  const float* out_w = (const float*)d_in[16];
  const float* out_b = (const float*)d_in[17];
  const int* input_ids = (const int*)d_in[18];
  const int* tag_ids  = (const int*)d_in[19];
  const int* lengths  = (const int*)d_in[20];
  float* dout = (float*)d_out;

  const dim3 gxg(TLEN, G3/64);

  // encoder L0 fwd
  gemm_gx<AM_ENC><<<gxg,256,0,stream>>>(enc_embed,0,0,input_ids,e0_wih,e0_bih,F_GX,HDIM);
  scan_kernel<false,false><<<NBLK,256,0,stream>>>(F_GX, F_T0, F_H0F, e0_whh, e0_bhh, lengths, F_OF0);
  // encoder L0 bwd
  gemm_gx<AM_ENC><<<gxg,256,0,stream>>>(enc_embed,0,0,input_ids,
                                        e0_wih+(u64)G3*HDIM, e0_bih+G3, F_GX, HDIM);
  scan_kernel<true,false><<<NBLK,256,0,stream>>>(F_GX, F_T0, F_H0B,
                                        e0_whh+(u64)G3*HDIM, e0_bhh+G3, lengths, F_OB0);
  // encoder L1 fwd
  gemm_gx<AM_CAT><<<gxg,256,0,stream>>>(nullptr, F_OF0, F_OB0, nullptr,
                                        e1_wih, e1_bih, F_GX, 2*HDIM);
  scan_kernel<false,false><<<NBLK,256,0,stream>>>(F_GX, F_T0, F_T1, e1_whh, e1_bhh, lengths, F_ENC);
  // encoder L1 bwd (accumulate)
  gemm_gx<AM_CAT><<<gxg,256,0,stream>>>(nullptr, F_OF0, F_OB0, nullptr,
                                        e1_wih+(u64)G3*2*HDIM, e1_bih+G3, F_GX, 2*HDIM);
  scan_kernel<true,true><<<NBLK,256,0,stream>>>(F_GX, F_T0, F_T1,
                                        e1_whh+(u64)G3*HDIM, e1_bhh+G3, lengths, F_ENC);
  // decoder
  gemm_gx<AM_DEC><<<gxg,256,0,stream>>>(dec_embed,0,0,tag_ids, d_wih, d_bih, F_GX, HDIM);
  decoder_kernel<<<NBLK,256,0,stream>>>(d_whh, d_bhh,
                                        d_wih+(u64)G3*HDIM, d_bih+G3,
                                        d_whh+(u64)G3*HDIM, d_bhh+G3,
                                        concat_w, concat_b, out_w, out_b,
                                        tag_ids, lengths, dout);
}

// Round 11
// 45082.959 us; speedup vs baseline: 1.7279x; 1.7279x over previous
//
#include <hip/hip_runtime.h>
#include <math.h>

#define HDIM 1024
#define NTAG 256
#define BSZ 128
#define TLEN 50
#define G3 3072
#define NBLK 256
#define NGRP 8

typedef unsigned long long u64;
typedef unsigned short u16;

// ---- static f32 pool, recurrent tensors transposed [k][b] ----
constexpr u64 GX_F  = (u64)TLEN*G3*BSZ;     // gx [t][n][b]
constexpr u64 SEQ_F = (u64)TLEN*HDIM*BSZ;   // [t][k][b]
constexpr u64 HST_F = (u64)HDIM*BSZ;        // h [k][b]
constexpr u64 F_GX  = 0;
constexpr u64 F_OF0 = F_GX + GX_F;
constexpr u64 F_OB0 = F_OF0 + SEQ_F;
constexpr u64 F_ENC = F_OB0 + SEQ_F;
constexpr u64 F_T0  = F_ENC + SEQ_F;
constexpr u64 F_T1  = F_T0 + HST_F;
constexpr u64 F_H0F = F_T1 + HST_F;
constexpr u64 F_H0B = F_H0F + HST_F;
constexpr u64 F_D0A = F_H0B + HST_F;
constexpr u64 F_D0B = F_D0A + HST_F;
constexpr u64 F_D1A = F_D0B + HST_F;
constexpr u64 F_D1B = F_D1A + HST_F;
constexpr u64 F_CTX = F_D1B + HST_F;
constexpr u64 F_CC  = F_CTX + HST_F;
constexpr u64 F_LG  = F_CC + HST_F;                 // logits [v][b]
constexpr u64 F_QP  = F_LG + (u64)NTAG*BSZ;
constexpr u64 F_A   = F_QP + (u64)8*TLEN*BSZ;
constexpr u64 F_NLL = F_A + (u64)TLEN*BSZ;
constexpr u64 POOL_F= F_NLL + (u64)TLEN*BSZ;

__device__ __align__(256) float g_pool[POOL_F];
__device__ unsigned g_grp[NGRP*32];
__device__ unsigned g_root;
__device__ unsigned g_gen;

__device__ __forceinline__ float sigmf(float x){ return 1.f/(1.f+__expf(-x)); }
__device__ __forceinline__ u16 f2b(float x){
  unsigned u = __float_as_uint(x);
  u += 0x7fffu + ((u>>16)&1u);
  return (u16)(u>>16);
}
__device__ __forceinline__ float b2f(u16 s){ return __uint_as_float(((unsigned)s)<<16); }

// two-level tree barrier: 8 padded group counters + root (256 blocks, 1/CU)
__device__ __forceinline__ void grid_sync(){
  __syncthreads();
  if (threadIdx.x == 0){
    __threadfence();
    const int g = blockIdx.x & (NGRP-1);
    unsigned gen = __hip_atomic_load(&g_gen, __ATOMIC_RELAXED, __HIP_MEMORY_SCOPE_AGENT);
    unsigned old = __hip_atomic_fetch_add(&g_grp[g*32], 1u, __ATOMIC_ACQ_REL, __HIP_MEMORY_SCOPE_AGENT);
    if (old == (NBLK/NGRP)-1){
      unsigned ro = __hip_atomic_fetch_add(&g_root, 1u, __ATOMIC_ACQ_REL, __HIP_MEMORY_SCOPE_AGENT);
      if (ro == NGRP-1){
        __hip_atomic_store(&g_root, 0u, __ATOMIC_RELAXED, __HIP_MEMORY_SCOPE_AGENT);
        #pragma unroll
        for (int i=0;i<NGRP;++i)
          __hip_atomic_store(&g_grp[i*32], 0u, __ATOMIC_RELAXED, __HIP_MEMORY_SCOPE_AGENT);
        __hip_atomic_fetch_add(&g_gen, 1u, __ATOMIC_ACQ_REL, __HIP_MEMORY_SCOPE_AGENT);
      } else {
        while (__hip_atomic_load(&g_gen, __ATOMIC_ACQUIRE, __HIP_MEMORY_SCOPE_AGENT) == gen)
          __builtin_amdgcn_s_sleep(2);
      }
    } else {
      while (__hip_atomic_load(&g_gen, __ATOMIC_ACQUIRE, __HIP_MEMORY_SCOPE_AGENT) == gen)
        __builtin_amdgcn_s_sleep(2);
    }
    __threadfence();
  }
  __syncthreads();
}

// (round-9) full-K partial GEMM for scans: 6 rows, k split across 4 waves, W in LDS
template<int R, int KPW, bool WLDS>
__device__ __forceinline__ void gfk(const float* __restrict__ wl,
                                    const float* __restrict__ Wg, int ldw,
                                    const int* rows,
                                    const float* __restrict__ aT0,
                                    const float* __restrict__ aT1, int K0,
                                    float acc[R][2], int tid)
{
  const int w = tid>>6, l2 = (tid&63)*2;
  #pragma unroll
  for (int r=0;r<R;++r){ acc[r][0]=0.f; acc[r][1]=0.f; }
  const int k0 = w*KPW;
  const float* ap = ((k0 < K0)? (aT0 + (u64)k0*BSZ) : (aT1 + (u64)(k0-K0)*BSZ)) + l2;
  const float* wg[R];
  if constexpr (!WLDS){
    #pragma unroll
    for (int r=0;r<R;++r) wg[r] = Wg + (u64)rows[r]*ldw + k0;
  }
  const float* wp = WLDS ? (wl + (u64)k0*R) : nullptr;
  for (int kb=0; kb<KPW; kb+=8){
    float2 a[8];
    #pragma unroll
    for (int u=0;u<8;++u) a[u] = *(const float2*)(ap + (u64)(kb+u)*BSZ);
    #pragma unroll
    for (int u=0;u<8;++u){
      #pragma unroll
      for (int r=0;r<R;++r){
        float wv;
        if constexpr (WLDS) wv = wp[(u64)(kb+u)*R + r];
        else                wv = wg[r][kb+u];
        acc[r][0] += wv*a[u].x; acc[r][1] += wv*a[u].y;
      }
    }
  }
}

template<int R>
__device__ __forceinline__ void reduceR(const float acc[R][2], float* red, int tid){
  const int w = tid>>6, l2 = (tid&63)*2;
  __syncthreads();
  #pragma unroll
  for (int r=0;r<R;++r){
    red[(u64)(w*R+r)*128 + l2]   = acc[r][0];
    red[(u64)(w*R+r)*128 + l2+1] = acc[r][1];
  }
  __syncthreads();
}

#define AM_ENC 0
#define AM_DEC 1
#define AM_CAT 2

// gx[(t*G3+n)*BSZ+b] = A[t,b,:] @ W[n,:]^T + bias[n]  (round-9 verbatim)
template<int AMODE>
__global__ __launch_bounds__(256)
void gemm_gx(const float* __restrict__ embed,
             u64 a1_f, u64 a2_f,
             const int* __restrict__ ids,
             const float* __restrict__ W,
             const float* __restrict__ bias,
             u64 c_f, int K)
{
  constexpr int TM=128, TN=64, TK=32;
  __shared__ float As[TK][TM+4];
  __shared__ float Ws[TK][TN+4];
  __shared__ int rowid[TM];
  const int t = blockIdx.x;
  const int n0 = blockIdx.y*TN;
  const int tid = threadIdx.x;

  if (AMODE != AM_CAT){
    for (int r=tid; r<TM; r+=256)
      rowid[r] = (AMODE==AM_ENC) ? ids[r*TLEN+t] : ((t==0)?1:ids[r*TLEN+t-1]);
    __syncthreads();
  }

  const int tm = tid>>4, tn = tid&15;
  float acc[8][4];
  #pragma unroll
  for (int i=0;i<8;i++){ acc[i][0]=0.f;acc[i][1]=0.f;acc[i][2]=0.f;acc[i][3]=0.f; }

  for (int k0=0;k0<K;k0+=TK){
    if (AMODE==AM_CAT){
      const int kk = tid>>3, q = tid&7;
      const int kg = k0 + kk;
      const float* src = g_pool + ((kg<HDIM)? (a1_f + ((u64)t*HDIM + kg)*BSZ)
                                            : (a2_f + ((u64)t*HDIM + (kg-HDIM))*BSZ)) + q*16;
      float* d = &As[kk][q*16];
      float4 v0=*(const float4*)(src+0), v1=*(const float4*)(src+4);
      float4 v2=*(const float4*)(src+8), v3=*(const float4*)(src+12);
      *(float4*)(d+0)=v0; *(float4*)(d+4)=v1; *(float4*)(d+8)=v2; *(float4*)(d+12)=v3;
    } else {
      #pragma unroll
      for (int l=tid; l<TM*TK; l+=256){
        int r=l>>5, k=l&31;
        As[k][r] = embed[(u64)rowid[r]*HDIM + k0 + k];
      }
    }
    #pragma unroll
    for (int l=tid; l<TN*TK; l+=256){
      int n=l>>5, k=l&31;
      Ws[k][n] = W[(u64)(n0+n)*K + k0 + k];
    }
    __syncthreads();
    #pragma unroll 8
    for (int kk=0;kk<TK;kk++){
      float4 a0 = *(const float4*)&As[kk][tm*8];
      float4 a1 = *(const float4*)&As[kk][tm*8+4];
      float4 w  = *(const float4*)&Ws[kk][tn*4];
      float av[8]={a0.x,a0.y,a0.z,a0.w,a1.x,a1.y,a1.z,a1.w};
      float wv[4]={w.x,w.y,w.z,w.w};
      #pragma unroll
      for (int i=0;i<8;i++){
        #pragma unroll
        for (int jj=0;jj<4;jj++) acc[i][jj] += av[i]*wv[jj];
      }
    }
    __syncthreads();
  }

  float bv[4];
  #pragma unroll
  for (int jj=0;jj<4;jj++) bv[jj] = bias[n0+tn*4+jj];
  float* C = g_pool + c_f;
  for (int half=0; half<2; ++half){
    if ((tn>>3)==half){
      #pragma unroll
      for (int i=0;i<8;i++)
        #pragma unroll
        for (int jj=0;jj<4;jj++)
          As[(tn&7)*4+jj][tm*8+i] = acc[i][jj]+bv[jj];
    }
    __syncthreads();
    {
      const int nn = tid>>3, q = tid&7;
      float* dst = C + ((u64)t*G3 + n0 + half*32 + nn)*BSZ + q*16;
      const float* srow = &As[nn][q*16];
      float4 v0=*(const float4*)(srow+0), v1=*(const float4*)(srow+4);
      float4 v2=*(const float4*)(srow+8), v3=*(const float4*)(srow+12);
      *(float4*)(dst+0)=v0; *(float4*)(dst+4)=v1; *(float4*)(dst+8)=v2; *(float4*)(dst+12)=v3;
    }
    __syncthreads();
  }
}

// persistent masked GRU scan (round-9 verbatim): 256 blocks, 4 j-cols, 1 barrier/step
template<bool BWD, bool ACCUM>
__global__ __launch_bounds__(256)
void scan_kernel(u64 gx_f, u64 p0_f, u64 p1_f,
                 const float* __restrict__ whh, const float* __restrict__ bhh,
                 const int* __restrict__ lengths, u64 out_f)
{
  __shared__ float wl[HDIM*6];
  __shared__ float red[4*6*128];
  const int bid = blockIdx.x, tid = threadIdx.x;
  const int j0 = bid*4;
  // NOTE: round-9 scan had 2 j per block over 512 blocks? No — this is the 256-block/4-col variant:
  // rows = 3 gates x 2 j? Keep EXACT round-9: 2 j-cols -> but NBLK=256 covers 512... use 4 j with R=6? 
  // Round 9 used bid*4 with R=6 rows? It used j0=bid*4 and rows (r>>2)... That was round 8.
  // Round 9: j0 = bid*4, 12 rows, gemmfk. Here: re-derived 256-block variant with R=6 over 2 j is wrong.
  // Correct: 4 j-cols, 12 rows -> but gfk is R-generic; use R=12? LDS wl[HDIM*12]=48KB. Use that.
  (void)wl; (void)red;
}

// real scan (4 j-cols, 12 rows, k-split waves, 1 barrier/step)
template<bool BWD, bool ACCUM>
__global__ __launch_bounds__(256)
void scan_kernel2(u64 gx_f, u64 p0_f, u64 p1_f,
                  const float* __restrict__ whh, const float* __restrict__ bhh,
                  const int* __restrict__ lengths, u64 out_f)
{
  __shared__ float wl[HDIM*12];      // 48 KB
  __shared__ float red[4*12*128];    // 24 KB
  const int bid = blockIdx.x, tid = threadIdx.x;
  const int j0 = bid*4;
  #pragma unroll
  for (int r=0;r<12;++r){
    const int row = (r>>2)*HDIM + j0 + (r&3);
    for (int k=tid;k<HDIM;k+=256) wl[k*12+r] = whh[(u64)row*HDIM + k];
  }
  __syncthreads();

  const int jj = tid>>7, bb = tid&127;   // jj in 0..1 covers 2 of 4 j per thread-pass
  for (int s=0; s<TLEN; ++s){
    const int t = BWD ? (TLEN-1-s) : s;
    const u64 rd = (s&1)? p0_f : p1_f;
    const u64 wr = (s&1)? p1_f : p0_f;
    if (s>0){
      float acc[12][2];
      gfk<12,256,true>(wl, nullptr, 0, nullptr, g_pool+rd, g_pool+rd, 1<<28, acc, tid);
      reduceR<12>(acc, red, tid);
    }
    const float* gxb = g_pool + gx_f + (u64)t*G3*BSZ;
    #pragma unroll
    for (int jp=0;jp<2;++jp){
      const int jl = jj*2 + jp;          // 0..3
      const int jg = j0 + jl;
      const int len = lengths[bb];
      const bool m = (t < len);
      float gh[3] = {0.f,0.f,0.f};
      if (s>0){
        #pragma unroll
        for (int g=0;g<3;++g){
          const int r = g*4 + jl;
          float sum = red[(u64)(0*12+r)*128+bb] + red[(u64)(1*12+r)*128+bb];
          sum += red[(u64)(2*12+r)*128+bb] + red[(u64)(3*12+r)*128+bb];
          gh[g] = sum;
        }
      }
      const float xr = gxb[(u64)jg*BSZ + bb];
      const float xz = gxb[(u64)(HDIM+jg)*BSZ + bb];
      const float xn = gxb[(u64)(2*HDIM+jg)*BSZ + bb];
      const float hp = (s>0)? g_pool[rd + (u64)jg*BSZ + bb] : 0.f;
      const float r = sigmf(xr + gh[0] + bhh[jg]);
      const float z = sigmf(xz + gh[1] + bhh[HDIM+jg]);
      const float n = tanhf(xn + r*(gh[2] + bhh[2*HDIM+jg]));
      const float hv = (1.f-z)*n + z*hp;
      g_pool[wr + (u64)jg*BSZ + bb] = m ? hv : hp;
      const u64 oidx = out_f + ((u64)t*HDIM + jg)*BSZ + bb;
      if (ACCUM){ if (m) g_pool[oidx] += hv; }
      else g_pool[oidx] = m ? hv : 0.f;
    }
    grid_sync();
  }
}

// decoder GRU-block GEMM: 24 rows in bf16 LDS wl[k][24], full-K per wave (rows w*6..)
__device__ __forceinline__ void ggemm24(const u16* __restrict__ wl,
                                        const float* __restrict__ aT,
                                        float (&acc)[6][2], int tid)
{
  const int w = tid>>6, l2 = (tid&63)*2;
  const int rbase = w*6;
  #pragma unroll
  for (int r=0;r<6;++r){ acc[r][0]=0.f; acc[r][1]=0.f; }
  for (int k=0;k<HDIM;k+=8){
    float2 a[8];
    #pragma unroll
    for (int u=0;u<8;++u) a[u] = *(const float2*)&aT[(u64)(k+u)*BSZ + l2];
    #pragma unroll
    for (int u=0;u<8;++u){
      const u16* wr = wl + (u64)(k+u)*24 + rbase;
      #pragma unroll
      for (int r=0;r<6;++r){
        const float wv = b2f(wr[r]);
        acc[r][0] += wv*a[u].x; acc[r][1] += wv*a[u].y;
      }
    }
  }
}

// persistent decoder: role-split LDS (attn blocks cache enc column; GRU blocks cache weights)
__global__ __launch_bounds__(256)
void decoder_kernel(const float* __restrict__ whh0, const float* __restrict__ bhh0,
                    const float* __restrict__ wih1, const float* __restrict__ bih1,
                    const float* __restrict__ whh1, const float* __restrict__ bhh1,
                    const float* __restrict__ cw, const float* __restrict__ cb,
                    const float* __restrict__ ow, const float* __restrict__ ob,
                    const int* __restrict__ tag_ids, const int* __restrict__ lengths,
                    float* __restrict__ dout)
{
  __shared__ __align__(16) unsigned char smem[159744];
  const int bid = blockIdx.x, tid = threadIdx.x;
  constexpr int SCR = 147456;

  // role-specific preload
  if (bid < 128){
    // attn block: encL bf16 [50][1024] for b=bid
    u16* encL = (u16*)smem;
    const int b = bid;
    for (int tp=0; tp<TLEN; ++tp)
      for (int k=tid; k<HDIM; k+=256)
        encL[(u64)tp*HDIM + k] = f2b(g_pool[F_ENC + ((u64)tp*HDIM + k)*BSZ + b]);
  } else {
    u16* wl0 = (u16*)smem;
    u16* wl1 = (u16*)(smem + 49152);
    u16* wl2 = (u16*)(smem + 98304);
    const int j0 = (bid-128)*8;
    #pragma unroll
    for (int r=0;r<24;++r){
      const int gr = (r>>3)*HDIM + j0 + (r&7);
      for (int k=tid;k<HDIM;k+=256){
        wl0[(u64)k*24+r] = f2b(whh0[(u64)gr*HDIM + k]);
        wl1[(u64)k*24+r] = f2b(wih1[(u64)gr*HDIM + k]);
        wl2[(u64)k*24+r] = f2b(whh1[(u64)gr*HDIM + k]);
      }
    }
  }
  __syncthreads();

  const int w = tid>>6, l2 = (tid&63)*2;

  for (int t=0; t<TLEN; ++t){
    const u64 h0c = (t==0)? F_H0F : ((t&1)? F_D0A : F_D0B);
    const u64 h0n = (t&1)? F_D0B : F_D0A;
    const u64 h1c = (t==0)? F_H0B : ((t&1)? F_D1A : F_D1B);
    const u64 h1n = (t&1)? F_D1B : F_D1A;

    // ---- P1: layer-0 GRU (GRU blocks) ----
    if (bid >= 128){
      const u16* wl0 = (const u16*)smem;
      const int j0 = (bid-128)*8;
      float acc[6][2];
      ggemm24(wl0, g_pool + h0c, acc, tid);
      float* s1 = (float*)(smem + SCR);       // [24][128]
      const int rbase = w*6;
      #pragma unroll
      for (int r=0;r<6;++r){
        s1[(u64)(rbase+r)*128 + l2]   = acc[r][0];
        s1[(u64)(rbase+r)*128 + l2+1] = acc[r][1];
      }
      __syncthreads();
      const float* gxb = g_pool + F_GX + (u64)t*G3*BSZ;
      for (int it=tid; it<1024; it+=256){
        const int jl = it>>7, b = it&127;
        const int jg = j0 + jl;
        const float ghr = s1[(u64)jl*128+b], ghz = s1[(u64)(8+jl)*128+b], ghn = s1[(u64)(16+jl)*128+b];
        const float xr = gxb[(u64)jg*BSZ+b], xz = gxb[(u64)(HDIM+jg)*BSZ+b], xn = gxb[(u64)(2*HDIM+jg)*BSZ+b];
        const float hp = g_pool[h0c + (u64)jg*BSZ + b];
        const float r = sigmf(xr + ghr + bhh0[jg]);
        const float z = sigmf(xz + ghz + bhh0[HDIM+jg]);
        const float n = tanhf(xn + r*(ghn + bhh0[2*HDIM+jg]));
        g_pool[h0n + (u64)jg*BSZ + b] = (1.f-z)*n + z*hp;
      }
    }
    grid_sync();   // b1

    // ---- P2: layer-1 GRU (GRU blocks, two GEMMs) ----
    if (bid >= 128){
      const u16* wl1 = (const u16*)(smem + 49152);
      const u16* wl2 = (const u16*)(smem + 98304);
      const int j0 = (bid-128)*8;
      float a1[6][2], a2[6][2];
      ggemm24(wl1, g_pool + h0n, a1, tid);
      ggemm24(wl2, g_pool + h1c, a2, tid);
      float* srz = (float*)(smem + SCR);          // [16][128] f32
      u16* sxn = (u16*)(smem + SCR + 8192);       // [8][128] bf16
      u16* shn = (u16*)(smem + SCR + 10240);      // [8][128] bf16
      const int rbase = w*6;
      #pragma unroll
      for (int r6=0;r6<6;++r6){
        const int r = rbase + r6, g = r>>3, jj = r&7;
        if (g < 2){
          srz[(u64)(g*8+jj)*128 + l2]   = a1[r6][0] + a2[r6][0];
          srz[(u64)(g*8+jj)*128 + l2+1] = a1[r6][1] + a2[r6][1];
        } else {
          sxn[(u64)jj*128 + l2]   = f2b(a1[r6][0]);
          sxn[(u64)jj*128 + l2+1] = f2b(a1[r6][1]);
          shn[(u64)jj*128 + l2]   = f2b(a2[r6][0]);
          shn[(u64)jj*128 + l2+1] = f2b(a2[r6][1]);
        }
      }
      __syncthreads();
      for (int it=tid; it<1024; it+=256){
        const int jl = it>>7, b = it&127;
        const int jg = j0 + jl;
        const float rsum = srz[(u64)jl*128+b];
        const float zsum = srz[(u64)(8+jl)*128+b];
        const float xn = b2f(sxn[(u64)jl*128+b]);
        const float hn = b2f(shn[(u64)jl*128+b]);
        const float hp = g_pool[h1c + (u64)jg*BSZ + b];
        const float r = sigmf(rsum + bih1[jg] + bhh1[jg]);
        const float z = sigmf(zsum + bih1[HDIM+jg] + bhh1[HDIM+jg]);
        const float n = tanhf(xn + bih1[2*HDIM+jg] + r*(hn + bhh1[2*HDIM+jg]));
        g_pool[h1n + (u64)jg*BSZ + b] = (1.f-z)*n + z*hp;
      }
    }
    grid_sync();   // b2

    // ---- ATTN: scores + softmax + ctx, enc in LDS (attn blocks) ----
    if (bid < 128){
      const int b = bid;
      const u16* encL = (const u16*)smem;
      float* h1L = (float*)(smem + 102400);
      float* sc  = (float*)(smem + 106496);
      float* aL  = (float*)(smem + 106752);
      for (int k=tid;k<HDIM;k+=256) h1L[k] = g_pool[h1n + (u64)k*BSZ + b];
      __syncthreads();
      const int l = tid&63;
      for (int tp=w; tp<TLEN; tp+=4){
        float s = 0.f;
        #pragma unroll
        for (int ii=0; ii<16; ++ii){
          const int k = l + ii*64;
          s += h1L[k]*b2f(encL[(u64)tp*HDIM + k]);
        }
        #pragma unroll
        for (int o=32;o;o>>=1) s += __shfl_xor(s, o);
        if (l==0) sc[tp] = s;
      }
      __syncthreads();
      if (tid < 64){
        float v = (tid<TLEN)? sc[tid] : -1e30f;
        float mx = v;
        #pragma unroll
        for (int o=32;o;o>>=1) mx = fmaxf(mx, __shfl_xor(mx,o));
        float e = (tid<TLEN)? __expf(v-mx) : 0.f;
        float sm = e;
        #pragma unroll
        for (int o=32;o;o>>=1) sm += __shfl_xor(sm,o);
        if (tid < TLEN) aL[tid] = e/sm;
      }
      __syncthreads();
      for (int k=tid;k<HDIM;k+=256){
        float acc = 0.f;
        #pragma unroll 10
        for (int tp=0;tp<TLEN;++tp) acc += aL[tp]*b2f(encL[(u64)tp*HDIM + k]);
        g_pool[F_CTX + (u64)k*BSZ + b] = acc;
      }
    }
    grid_sync();   // b3

    // ---- P5: cc (all blocks; wave w -> row bid*4+w, full K=2048) ----
    {
      const int n = bid*4 + w;
      const float* cwn = cw + (u64)n*(2*HDIM);
      const float* h1p = g_pool + h1n;
      const float* cxp = g_pool + F_CTX;
      float a0=0.f, a1v=0.f;
      for (int k=0;k<HDIM;k+=8){
        float2 av[8]; float wv[8];
        #pragma unroll
        for (int u=0;u<8;++u){ av[u] = *(const float2*)&h1p[(u64)(k+u)*BSZ + l2]; wv[u] = cwn[k+u]; }
        #pragma unroll
        for (int u=0;u<8;++u){ a0 += wv[u]*av[u].x; a1v += wv[u]*av[u].y; }
      }
      for (int k=0;k<HDIM;k+=8){
        float2 av[8]; float wv[8];
        #pragma unroll
        for (int u=0;u<8;++u){ av[u] = *(const float2*)&cxp[(u64)(k+u)*BSZ + l2]; wv[u] = cwn[HDIM+k+u]; }
        #pragma unroll
        for (int u=0;u<8;++u){ a0 += wv[u]*av[u].x; a1v += wv[u]*av[u].y; }
      }
      g_pool[F_CC + (u64)n*BSZ + l2]   = tanhf(a0 + cb[n]);
      g_pool[F_CC + (u64)n*BSZ + l2+1] = tanhf(a1v + cb[n]);
    }
    grid_sync();   // b4

    // ---- P6: logits row v=bid, K=1024 split in 2 halves over tid>>7 ----
    {
      float* scrf = (float*)(smem + SCR);
      const int b = tid&127, kh = tid>>7;
      const float* owv = ow + (u64)bid*HDIM + kh*512;
      const float* ccp = g_pool + F_CC + (u64)kh*512*BSZ;
      float acc = 0.f;
      for (int k=0;k<512;k+=8){
        float av[8]; float wv[8];
        #pragma unroll
        for (int u=0;u<8;++u){ av[u] = ccp[(u64)(k+u)*BSZ + b]; wv[u] = owv[k+u]; }
        #pragma unroll
        for (int u=0;u<8;++u) acc += wv[u]*av[u];
      }
      scrf[tid] = acc;
      __syncthreads();
      if (tid < 128){
        const float lg = ob[bid] + scrf[tid] + scrf[128+tid];
        g_pool[F_LG + (u64)bid*BSZ + tid] = lg;
      }
    }
    grid_sync();   // b5

    // ---- P7: per-b softmax + nll (attn blocks) ----
    if (bid < BSZ){
      float* lgs = (float*)(smem + SCR);
      float* rp  = lgs + 256;
      const int b = bid, v = tid;
      const float lg = g_pool[F_LG + (u64)v*BSZ + b];
      lgs[v] = lg; rp[v] = lg;
      __syncthreads();
      for (int o=128;o;o>>=1){ if (tid<o) rp[tid]=fmaxf(rp[tid],rp[tid+o]); __syncthreads(); }
      const float mx = rp[0];
      __syncthreads();
      rp[tid] = __expf(lg-mx);
      __syncthreads();
      for (int o=128;o;o>>=1){ if (tid<o) rp[tid]+=rp[tid+o]; __syncthreads(); }
      const float lse = mx + __logf(rp[0]);
      dout[((u64)b*TLEN + t)*NTAG + v] = lg;
      if (tid==0){
        const int tag = tag_ids[b*TLEN + t];
        g_pool[F_NLL + (u64)t*BSZ + b] = lse - lgs[tag];
      }
    }
    // no trailing barrier: next P1 (GRU blocks) touches only h/gx/own scr
  }
  grid_sync();
  // ---- loss ----
  if (bid == 0){
    float* rp = (float*)(smem + SCR);
    float ssum = 0.f;
    for (int i=tid; i<TLEN*BSZ; i+=256){
      const int tt = i>>7, b = i&127;
      if (tt < lengths[b]) ssum += g_pool[F_NLL + i];
    }
    rp[tid] = ssum; __syncthreads();
    for (int o=128;o;o>>=1){ if (tid<o) rp[tid]+=rp[tid+o]; __syncthreads(); }
    if (tid==0){
      int den=0;
      for (int b=0;b<BSZ;b++) den += lengths[b];
      dout[(u64)BSZ*TLEN*NTAG] = rp[0]/(float)den;
    }
  }
}

extern "C" void kernel_launch(void* const* d_in, const int* in_sizes, int n_in,
                              void* d_out, int out_size, void* d_ws, size_t ws_size,
                              hipStream_t stream)
{
  const float* enc_embed = (const float*)d_in[0];
  const float* e0_wih = (const float*)d_in[1];
  const float* e0_whh = (const float*)d_in[2];
  const float* e0_bih = (const float*)d_in[3];
  const float* e0_bhh = (const float*)d_in[4];
  const float* e1_wih = (const float*)d_in[5];
  const float* e1_whh = (const float*)d_in[6];
  const float* e1_bih = (const float*)d_in[7];
  const float* e1_bhh = (const float*)d_in[8];
  const float* dec_embed = (const float*)d_in[9];
  const float* d_wih = (const float*)d_in[10];
  const float* d_whh = (const float*)d_in[11];
  const float* d_bih = (const float*)d_in[12];
  const float* d_bhh = (const float*)d_in[13];
  const float* concat_w = (const float*)d_in[14];
  const float* concat_b = (const float*)d_in[15];
  const float* out_w = (const float*)d_in[16];
  const float* out_b = (const float*)d_in[17];
  const int* input_ids = (const int*)d_in[18];
  const int* tag_ids  = (const int*)d_in[19];
  const int* lengths  = (const int*)d_in[20];
  float* dout = (float*)d_out;

  const dim3 gxg(TLEN, G3/64);

  gemm_gx<AM_ENC><<<gxg,256,0,stream>>>(enc_embed,0,0,input_ids,e0_wih,e0_bih,F_GX,HDIM);
  scan_kernel2<false,false><<<NBLK,256,0,stream>>>(F_GX, F_T0, F_H0F, e0_whh, e0_bhh, lengths, F_OF0);
  gemm_gx<AM_ENC><<<gxg,256,0,stream>>>(enc_embed,0,0,input_ids,
                                        e0_wih+(u64)G3*HDIM, e0_bih+G3, F_GX, HDIM);
  scan_kernel2<true,false><<<NBLK,256,0,stream>>>(F_GX, F_T0, F_H0B,
                                        e0_whh+(u64)G3*HDIM, e0_bhh+G3, lengths, F_OB0);
  gemm_gx<AM_CAT><<<gxg,256,0,stream>>>(nullptr, F_OF0, F_OB0, nullptr,
                                        e1_wih, e1_bih, F_GX, 2*HDIM);
  scan_kernel2<false,false><<<NBLK,256,0,stream>>>(F_GX, F_T0, F_T1, e1_whh, e1_bhh, lengths, F_ENC);
  gemm_gx<AM_CAT><<<gxg,256,0,stream>>>(nullptr, F_OF0, F_OB0, nullptr,
                                        e1_wih+(u64)G3*2*HDIM, e1_bih+G3, F_GX, 2*HDIM);
  scan_kernel2<true,true><<<NBLK,256,0,stream>>>(F_GX, F_T0, F_T1,
                                        e1_whh+(u64)G3*HDIM, e1_bhh+G3, lengths, F_ENC);
  gemm_gx<AM_DEC><<<gxg,256,0,stream>>>(dec_embed,0,0,tag_ids, d_wih, d_bih, F_GX, HDIM);
  decoder_kernel<<<NBLK,256,0,stream>>>(d_whh, d_bhh,
                                        d_wih+(u64)G3*HDIM, d_bih+G3,
                                        d_whh+(u64)G3*HDIM, d_bhh+G3,
                                        concat_w, concat_b, out_w, out_b,
                                        tag_ids, lengths, dout);
}

// Round 12
// 37423.334 us; speedup vs baseline: 2.0815x; 1.2047x over previous
//
#include <hip/hip_runtime.h>
#include <math.h>

#define HDIM 1024
#define NTAG 256
#define BSZ 128
#define TLEN 50
#define G3 3072
#define NBLK 256
#define NGRP 8

typedef unsigned long long u64;
typedef unsigned short u16;

// ---- static f32 pool, recurrent tensors transposed [k][b] ----
constexpr u64 GX_F  = (u64)TLEN*G3*BSZ;
constexpr u64 SEQ_F = (u64)TLEN*HDIM*BSZ;
constexpr u64 HST_F = (u64)HDIM*BSZ;
constexpr u64 F_GX  = 0;
constexpr u64 F_OF0 = F_GX + GX_F;
constexpr u64 F_OB0 = F_OF0 + SEQ_F;
constexpr u64 F_ENC = F_OB0 + SEQ_F;
constexpr u64 F_T0  = F_ENC + SEQ_F;
constexpr u64 F_T1  = F_T0 + HST_F;
constexpr u64 F_H0F = F_T1 + HST_F;
constexpr u64 F_H0B = F_H0F + HST_F;
constexpr u64 F_D0A = F_H0B + HST_F;
constexpr u64 F_D0B = F_D0A + HST_F;
constexpr u64 F_D1A = F_D0B + HST_F;
constexpr u64 F_D1B = F_D1A + HST_F;
constexpr u64 F_CTX = F_D1B + HST_F;
constexpr u64 F_CC  = F_CTX + HST_F;
constexpr u64 F_LG  = F_CC + HST_F;                 // logits [v][b]
constexpr u64 F_QP  = F_LG + (u64)NTAG*BSZ;         // 2 x TLEN x BSZ score partials
constexpr u64 F_NLL = F_QP + (u64)2*TLEN*BSZ;
constexpr u64 F_H1T = F_NLL + (u64)TLEN*BSZ;        // u16 [128][1024] -> 65536 f32
constexpr u64 F_CWB = F_H1T + 65536;                // u16 1024x2048 -> 1048576 f32
constexpr u64 F_OWB = F_CWB + 1048576;              // u16 256x1024 -> 131072 f32
constexpr u64 F_ETB = F_OWB + 131072;               // u16 [128][50][1024] -> 3276800 f32
constexpr u64 POOL_F= F_ETB + 3276800;

__device__ __align__(256) float g_pool[POOL_F];
__device__ unsigned g_grp[NGRP*32];
__device__ unsigned g_root;
__device__ unsigned g_gen;

__device__ __forceinline__ float sigmf(float x){ return 1.f/(1.f+__expf(-x)); }
__device__ __forceinline__ u16 f2b(float x){
  unsigned u = __float_as_uint(x);
  u += 0x7fffu + ((u>>16)&1u);
  return (u16)(u>>16);
}
__device__ __forceinline__ float b2f(u16 s){ return __uint_as_float(((unsigned)s)<<16); }

__device__ __forceinline__ void grid_sync(){
  __syncthreads();
  if (threadIdx.x == 0){
    __threadfence();
    const int g = blockIdx.x & (NGRP-1);
    unsigned gen = __hip_atomic_load(&g_gen, __ATOMIC_RELAXED, __HIP_MEMORY_SCOPE_AGENT);
    unsigned old = __hip_atomic_fetch_add(&g_grp[g*32], 1u, __ATOMIC_ACQ_REL, __HIP_MEMORY_SCOPE_AGENT);
    if (old == (NBLK/NGRP)-1){
      unsigned ro = __hip_atomic_fetch_add(&g_root, 1u, __ATOMIC_ACQ_REL, __HIP_MEMORY_SCOPE_AGENT);
      if (ro == NGRP-1){
        __hip_atomic_store(&g_root, 0u, __ATOMIC_RELAXED, __HIP_MEMORY_SCOPE_AGENT);
        #pragma unroll
        for (int i=0;i<NGRP;++i)
          __hip_atomic_store(&g_grp[i*32], 0u, __ATOMIC_RELAXED, __HIP_MEMORY_SCOPE_AGENT);
        __hip_atomic_fetch_add(&g_gen, 1u, __ATOMIC_ACQ_REL, __HIP_MEMORY_SCOPE_AGENT);
      } else {
        while (__hip_atomic_load(&g_gen, __ATOMIC_ACQUIRE, __HIP_MEMORY_SCOPE_AGENT) == gen)
          __builtin_amdgcn_s_sleep(2);
      }
    } else {
      while (__hip_atomic_load(&g_gen, __ATOMIC_ACQUIRE, __HIP_MEMORY_SCOPE_AGENT) == gen)
        __builtin_amdgcn_s_sleep(2);
    }
    __threadfence();
  }
  __syncthreads();
}

// 12-row GEMM: bf16 W in LDS (wl[k*12+r]), KPW=256 per wave, 16-deep prefetch
__device__ __forceinline__ void ggemm12(const u16* __restrict__ wl,
                                        const float* __restrict__ aT,
                                        float (&acc)[12][2], int tid)
{
  const int w = tid>>6, l2 = (tid&63)*2;
  #pragma unroll
  for (int r=0;r<12;++r){ acc[r][0]=0.f; acc[r][1]=0.f; }
  const int k0 = w*256;
  const float* ap = aT + (u64)k0*BSZ + l2;
  const u16* wp = wl + k0*12;
  for (int kb=0; kb<256; kb+=16){
    float2 a[16];
    #pragma unroll
    for (int u=0;u<16;++u) a[u] = *(const float2*)(ap + (u64)(kb+u)*BSZ);
    #pragma unroll
    for (int u=0;u<16;++u){
      const u16* wr = wp + (kb+u)*12;
      #pragma unroll
      for (int r=0;r<12;++r){
        const float wv = b2f(wr[r]);
        acc[r][0] += wv*a[u].x; acc[r][1] += wv*a[u].y;
      }
    }
  }
}

__device__ __forceinline__ void reduce12(const float (&acc)[12][2], float* red, int tid){
  const int w = tid>>6, l2 = (tid&63)*2;
  __syncthreads();
  #pragma unroll
  for (int r=0;r<12;++r){
    red[(u64)(w*12+r)*128 + l2]   = acc[r][0];
    red[(u64)(w*12+r)*128 + l2+1] = acc[r][1];
  }
  __syncthreads();
}

#define AM_ENC 0
#define AM_DEC 1
#define AM_CAT 2

// gx[(t*G3+n)*BSZ+b] = A[t,b,:] @ W[n,:]^T + bias[n]  (unchanged)
template<int AMODE>
__global__ __launch_bounds__(256)
void gemm_gx(const float* __restrict__ embed,
             u64 a1_f, u64 a2_f,
             const int* __restrict__ ids,
             const float* __restrict__ W,
             const float* __restrict__ bias,
             u64 c_f, int K)
{
  constexpr int TM=128, TN=64, TK=32;
  __shared__ float As[TK][TM+4];
  __shared__ float Ws[TK][TN+4];
  __shared__ int rowid[TM];
  const int t = blockIdx.x;
  const int n0 = blockIdx.y*TN;
  const int tid = threadIdx.x;

  if (AMODE != AM_CAT){
    for (int r=tid; r<TM; r+=256)
      rowid[r] = (AMODE==AM_ENC) ? ids[r*TLEN+t] : ((t==0)?1:ids[r*TLEN+t-1]);
    __syncthreads();
  }

  const int tm = tid>>4, tn = tid&15;
  float acc[8][4];
  #pragma unroll
  for (int i=0;i<8;i++){ acc[i][0]=0.f;acc[i][1]=0.f;acc[i][2]=0.f;acc[i][3]=0.f; }

  for (int k0=0;k0<K;k0+=TK){
    if (AMODE==AM_CAT){
      const int kk = tid>>3, q = tid&7;
      const int kg = k0 + kk;
      const float* src = g_pool + ((kg<HDIM)? (a1_f + ((u64)t*HDIM + kg)*BSZ)
                                            : (a2_f + ((u64)t*HDIM + (kg-HDIM))*BSZ)) + q*16;
      float* d = &As[kk][q*16];
      float4 v0=*(const float4*)(src+0), v1=*(const float4*)(src+4);
      float4 v2=*(const float4*)(src+8), v3=*(const float4*)(src+12);
      *(float4*)(d+0)=v0; *(float4*)(d+4)=v1; *(float4*)(d+8)=v2; *(float4*)(d+12)=v3;
    } else {
      #pragma unroll
      for (int l=tid; l<TM*TK; l+=256){
        int r=l>>5, k=l&31;
        As[k][r] = embed[(u64)rowid[r]*HDIM + k0 + k];
      }
    }
    #pragma unroll
    for (int l=tid; l<TN*TK; l+=256){
      int n=l>>5, k=l&31;
      Ws[k][n] = W[(u64)(n0+n)*K + k0 + k];
    }
    __syncthreads();
    #pragma unroll 8
    for (int kk=0;kk<TK;kk++){
      float4 a0 = *(const float4*)&As[kk][tm*8];
      float4 a1 = *(const float4*)&As[kk][tm*8+4];
      float4 w  = *(const float4*)&Ws[kk][tn*4];
      float av[8]={a0.x,a0.y,a0.z,a0.w,a1.x,a1.y,a1.z,a1.w};
      float wv[4]={w.x,w.y,w.z,w.w};
      #pragma unroll
      for (int i=0;i<8;i++){
        #pragma unroll
        for (int jj=0;jj<4;jj++) acc[i][jj] += av[i]*wv[jj];
      }
    }
    __syncthreads();
  }

  float bv[4];
  #pragma unroll
  for (int jj=0;jj<4;jj++) bv[jj] = bias[n0+tn*4+jj];
  float* C = g_pool + c_f;
  for (int half=0; half<2; ++half){
    if ((tn>>3)==half){
      #pragma unroll
      for (int i=0;i<8;i++)
        #pragma unroll
        for (int jj=0;jj<4;jj++)
          As[(tn&7)*4+jj][tm*8+i] = acc[i][jj]+bv[jj];
    }
    __syncthreads();
    {
      const int nn = tid>>3, q = tid&7;
      float* dst = C + ((u64)t*G3 + n0 + half*32 + nn)*BSZ + q*16;
      const float* srow = &As[nn][q*16];
      float4 v0=*(const float4*)(srow+0), v1=*(const float4*)(srow+4);
      float4 v2=*(const float4*)(srow+8), v3=*(const float4*)(srow+12);
      *(float4*)(dst+0)=v0; *(float4*)(dst+4)=v1; *(float4*)(dst+8)=v2; *(float4*)(dst+12)=v3;
    }
    __syncthreads();
  }
}

// persistent masked GRU scan: 256 blocks x 4 j-cols, bf16 LDS weights, 1 barrier/step
template<bool BWD, bool ACCUM>
__global__ __launch_bounds__(256)
void scan_kernel(u64 gx_f, u64 p0_f, u64 p1_f,
                 const float* __restrict__ whh, const float* __restrict__ bhh,
                 const int* __restrict__ lengths, u64 out_f)
{
  __shared__ u16 wl[HDIM*12];       // 24 KB
  __shared__ float red[4*12*128];   // 24 KB
  const int bid = blockIdx.x, tid = threadIdx.x;
  const int j0 = bid*4;
  #pragma unroll
  for (int r=0;r<12;++r){
    const int row = (r>>2)*HDIM + j0 + (r&3);
    for (int k=tid;k<HDIM;k+=256) wl[k*12+r] = f2b(whh[(u64)row*HDIM + k]);
  }
  __syncthreads();

  for (int s=0; s<TLEN; ++s){
    const int t = BWD ? (TLEN-1-s) : s;
    const u64 rd = (s&1)? p0_f : p1_f;
    const u64 wr = (s&1)? p1_f : p0_f;
    if (s>0){
      float acc[12][2];
      ggemm12(wl, g_pool + rd, acc, tid);
      reduce12(acc, red, tid);
    }
    const float* gxb = g_pool + gx_f + (u64)t*G3*BSZ;
    for (int it=tid; it<512; it+=256){
      const int jl = it>>7, b = it&127;
      const int jg = j0 + jl;
      const int len = lengths[b];
      const bool m = (t < len);
      float gh0=0.f, gh1=0.f, gh2=0.f;
      if (s>0){
        #pragma unroll
        for (int w2=0;w2<4;++w2){
          gh0 += red[(u64)(w2*12 + jl)*128 + b];
          gh1 += red[(u64)(w2*12 + 4 + jl)*128 + b];
          gh2 += red[(u64)(w2*12 + 8 + jl)*128 + b];
        }
      }
      const float xr = gxb[(u64)jg*BSZ + b];
      const float xz = gxb[(u64)(HDIM+jg)*BSZ + b];
      const float xn = gxb[(u64)(2*HDIM+jg)*BSZ + b];
      const float hp = (s>0)? g_pool[rd + (u64)jg*BSZ + b] : 0.f;
      const float r = sigmf(xr + gh0 + bhh[jg]);
      const float z = sigmf(xz + gh1 + bhh[HDIM+jg]);
      const float n = tanhf(xn + r*(gh2 + bhh[2*HDIM+jg]));
      const float hv = (1.f-z)*n + z*hp;
      g_pool[wr + (u64)jg*BSZ + b] = m ? hv : hp;
      const u64 oidx = out_f + ((u64)t*HDIM + jg)*BSZ + b;
      if (ACCUM){ if (m) g_pool[oidx] += hv; }
      else g_pool[oidx] = m ? hv : 0.f;
    }
    grid_sync();
  }
}

// one-time converters
__global__ __launch_bounds__(256)
void conv_w(const float* __restrict__ cw, const float* __restrict__ ow){
  u16* cwb = (u16*)(g_pool + F_CWB);
  u16* owb = (u16*)(g_pool + F_OWB);
  const u64 n1 = (u64)HDIM*2*HDIM;
  const u64 n2 = (u64)NTAG*HDIM;
  for (u64 i = (u64)blockIdx.x*256+threadIdx.x; i<n1; i += (u64)gridDim.x*256) cwb[i]=f2b(cw[i]);
  for (u64 i = (u64)blockIdx.x*256+threadIdx.x; i<n2; i += (u64)gridDim.x*256) owb[i]=f2b(ow[i]);
}
__global__ __launch_bounds__(256)
void enc_t(){
  const int t = blockIdx.x, kc = blockIdx.y;
  u16* etb = (u16*)(g_pool + F_ETB);
  for (int it=threadIdx.x; it<128*128; it+=256){
    const int kl = it>>7, b = it&127;
    const int k = kc*128 + kl;
    etb[(u64)b*(TLEN*HDIM) + (u64)t*HDIM + k] = f2b(g_pool[F_ENC + ((u64)t*HDIM+k)*BSZ + b]);
  }
}

// persistent decoder: every block = GRU slice (4 j) + attn half-column (b=bid>>1, kh=bid&1)
__global__ __launch_bounds__(256)
void decoder_kernel(const float* __restrict__ whh0, const float* __restrict__ bhh0,
                    const float* __restrict__ wih1, const float* __restrict__ bih1,
                    const float* __restrict__ whh1, const float* __restrict__ bhh1,
                    const float* __restrict__ cb, const float* __restrict__ ob,
                    const int* __restrict__ tag_ids, const int* __restrict__ lengths,
                    float* __restrict__ dout)
{
  __shared__ u16 wl0[HDIM*12];      // 24 KB
  __shared__ u16 wl1[HDIM*12];
  __shared__ u16 wl2[HDIM*12];
  __shared__ u16 encL[TLEN*512];    // 50 KB
  __shared__ float red[4*12*128];   // 24 KB
  __shared__ float aL[64];
  const int bid = blockIdx.x, tid = threadIdx.x;
  const int j0 = bid*4;
  const int ab = bid>>1, kh2 = bid&1;
  const int w = tid>>6, l2 = (tid&63)*2, l = tid&63;

  // preload weights (coalesced) + enc half-column (from pre-transposed bf16)
  #pragma unroll
  for (int r=0;r<12;++r){
    const int gr = (r>>2)*HDIM + j0 + (r&3);
    for (int k=tid;k<HDIM;k+=256){
      wl0[k*12+r] = f2b(whh0[(u64)gr*HDIM + k]);
      wl1[k*12+r] = f2b(wih1[(u64)gr*HDIM + k]);
      wl2[k*12+r] = f2b(whh1[(u64)gr*HDIM + k]);
    }
  }
  {
    const u16* etb = (const u16*)(g_pool + F_ETB);
    for (int tp=0; tp<TLEN; ++tp){
      const u16* src = etb + (u64)ab*(TLEN*HDIM) + (u64)tp*HDIM + kh2*512;
      for (int i=tid*2; i<512; i+=512)
        *(unsigned*)&encL[tp*512 + i] = *(const unsigned*)&src[i];
    }
  }
  __syncthreads();

  u16* h1t = (u16*)(g_pool + F_H1T);

  for (int t=0; t<TLEN; ++t){
    const u64 h0c = (t==0)? F_H0F : ((t&1)? F_D0A : F_D0B);
    const u64 h0n = (t&1)? F_D0B : F_D0A;
    const u64 h1c = (t==0)? F_H0B : ((t&1)? F_D1A : F_D1B);
    const u64 h1n = (t&1)? F_D1B : F_D1A;

    // ---- P1: layer-0 GRU ----
    {
      float acc[12][2];
      ggemm12(wl0, g_pool + h0c, acc, tid);
      reduce12(acc, red, tid);
      const float* gxb = g_pool + F_GX + (u64)t*G3*BSZ;
      for (int it=tid; it<512; it+=256){
        const int jl = it>>7, b = it&127;
        const int jg = j0 + jl;
        float gh0=0.f, gh1=0.f, gh2=0.f;
        #pragma unroll
        for (int w2=0;w2<4;++w2){
          gh0 += red[(u64)(w2*12 + jl)*128 + b];
          gh1 += red[(u64)(w2*12 + 4 + jl)*128 + b];
          gh2 += red[(u64)(w2*12 + 8 + jl)*128 + b];
        }
        const float xr = gxb[(u64)jg*BSZ+b], xz = gxb[(u64)(HDIM+jg)*BSZ+b], xn = gxb[(u64)(2*HDIM+jg)*BSZ+b];
        const float hp = g_pool[h0c + (u64)jg*BSZ + b];
        const float r = sigmf(xr + gh0 + bhh0[jg]);
        const float z = sigmf(xz + gh1 + bhh0[HDIM+jg]);
        const float n = tanhf(xn + r*(gh2 + bhh0[2*HDIM+jg]));
        g_pool[h0n + (u64)jg*BSZ + b] = (1.f-z)*n + z*hp;
      }
    }
    grid_sync();   // b1

    // ---- P2: layer-1 GRU (two GEMMs) ----
    {
      float acc[12][2];
      float aX[2][3], aH[2][3];
      ggemm12(wl1, g_pool + h0n, acc, tid);
      reduce12(acc, red, tid);
      #pragma unroll
      for (int q=0;q<2;++q){
        const int it = tid + q*256;
        const int jl = it>>7, b = it&127;
        #pragma unroll
        for (int g=0;g<3;++g){
          float s=0.f;
          #pragma unroll
          for (int w2=0;w2<4;++w2) s += red[(u64)(w2*12 + g*4 + jl)*128 + b];
          aX[q][g] = s;
        }
      }
      ggemm12(wl2, g_pool + h1c, acc, tid);
      reduce12(acc, red, tid);
      #pragma unroll
      for (int q=0;q<2;++q){
        const int it = tid + q*256;
        const int jl = it>>7, b = it&127;
        #pragma unroll
        for (int g=0;g<3;++g){
          float s=0.f;
          #pragma unroll
          for (int w2=0;w2<4;++w2) s += red[(u64)(w2*12 + g*4 + jl)*128 + b];
          aH[q][g] = s;
        }
      }
      #pragma unroll
      for (int q=0;q<2;++q){
        const int it = tid + q*256;
        const int jl = it>>7, b = it&127;
        const int jg = j0 + jl;
        const float hp = g_pool[h1c + (u64)jg*BSZ + b];
        const float r = sigmf(aX[q][0] + bih1[jg] + aH[q][0] + bhh1[jg]);
        const float z = sigmf(aX[q][1] + bih1[HDIM+jg] + aH[q][1] + bhh1[HDIM+jg]);
        const float n = tanhf(aX[q][2] + bih1[2*HDIM+jg] + r*(aH[q][2] + bhh1[2*HDIM+jg]));
        const float hv = (1.f-z)*n + z*hp;
        g_pool[h1n + (u64)jg*BSZ + b] = hv;
        h1t[(u64)b*HDIM + jg] = f2b(hv);
      }
    }
    grid_sync();   // b2

    // ---- P3: score partials (block = (b, k-half)) ----
    {
      const u16* h1r = h1t + (u64)ab*HDIM + kh2*512 + l*8;
      float hv[8];
      #pragma unroll
      for (int u=0;u<8;++u) hv[u] = b2f(h1r[u]);
      for (int tp=w; tp<TLEN; tp+=4){
        const u16* er = &encL[tp*512 + l*8];
        float s=0.f;
        #pragma unroll
        for (int u=0;u<8;++u) s += hv[u]*b2f(er[u]);
        #pragma unroll
        for (int o=32;o;o>>=1) s += __shfl_xor(s, o);
        if (l==0) g_pool[F_QP + (u64)kh2*TLEN*BSZ + (u64)tp*BSZ + ab] = s;
      }
    }
    grid_sync();   // b3

    // ---- P4: softmax (redundant per pair) + ctx half ----
    {
      if (tid < 64){
        float v = -1e30f;
        if (tid < TLEN)
          v = g_pool[F_QP + (u64)tid*BSZ + ab] + g_pool[F_QP + (u64)(TLEN+tid)*BSZ + ab];
        float mx = v;
        #pragma unroll
        for (int o=32;o;o>>=1) mx = fmaxf(mx, __shfl_xor(mx,o));
        float e = (tid<TLEN)? __expf(v-mx) : 0.f;
        float sm = e;
        #pragma unroll
        for (int o=32;o;o>>=1) sm += __shfl_xor(sm,o);
        if (tid < TLEN) aL[tid] = e/sm;
      }
      __syncthreads();
      for (int kk=tid; kk<512; kk+=256){
        float acc = 0.f;
        #pragma unroll 10
        for (int tp=0;tp<TLEN;++tp) acc += aL[tp]*b2f(encL[tp*512+kk]);
        g_pool[F_CTX + (u64)(kh2*512+kk)*BSZ + ab] = acc;
      }
    }
    grid_sync();   // b4

    // ---- P5: cc (wave = 2 rows x K-half, bf16 cw) ----
    {
      const int p = w>>1, kh = w&1;
      const int rA = bid*4 + p*2, rB = rA+1;
      const u16* cwb = (const u16*)(g_pool + F_CWB);
      const float* asrc = kh? (g_pool + F_CTX) : (g_pool + h1n);
      const u16* wAp = cwb + (u64)rA*2048 + kh*1024;
      const u16* wBp = cwb + (u64)rB*2048 + kh*1024;
      float aA0=0.f,aA1=0.f,aB0=0.f,aB1=0.f;
      for (int kb=0; kb<1024; kb+=16){
        float2 a[16];
        #pragma unroll
        for (int u=0;u<16;++u) a[u] = *(const float2*)&asrc[(u64)(kb+u)*BSZ + l2];
        #pragma unroll
        for (int u=0;u<16;++u){
          const float wA=b2f(wAp[kb+u]), wB=b2f(wBp[kb+u]);
          aA0+=wA*a[u].x; aA1+=wA*a[u].y;
          aB0+=wB*a[u].x; aB1+=wB*a[u].y;
        }
      }
      __syncthreads();
      red[(u64)(w*2+0)*128 + l2]   = aA0;
      red[(u64)(w*2+0)*128 + l2+1] = aA1;
      red[(u64)(w*2+1)*128 + l2]   = aB0;
      red[(u64)(w*2+1)*128 + l2+1] = aB1;
      __syncthreads();
      for (int it=tid; it<512; it+=256){
        const int ri = it>>7, b = it&127;
        const int p2 = ri>>1, q = ri&1;
        const int n = bid*4 + ri;
        const float s = red[(u64)((2*p2)*2+q)*128 + b] + red[(u64)((2*p2+1)*2+q)*128 + b];
        g_pool[F_CC + (u64)n*BSZ + b] = tanhf(s + cb[n]);
      }
    }
    grid_sync();   // b5

    // ---- P6: logits row v=bid (4-way k-split, bf16 ow) ----
    {
      const u16* owv = (const u16*)(g_pool + F_OWB) + (u64)bid*HDIM + w*256;
      const float* ccp = g_pool + F_CC + (u64)w*256*BSZ;
      float a0=0.f, a1v=0.f;
      for (int kb=0; kb<256; kb+=16){
        float2 a[16];
        #pragma unroll
        for (int u=0;u<16;++u) a[u] = *(const float2*)&ccp[(u64)(kb+u)*BSZ + l2];
        #pragma unroll
        for (int u=0;u<16;++u){
          const float wv = b2f(owv[kb+u]);
          a0 += wv*a[u].x; a1v += wv*a[u].y;
        }
      }
      __syncthreads();
      red[(u64)w*128 + l2]   = a0;
      red[(u64)w*128 + l2+1] = a1v;
      __syncthreads();
      if (tid < 128){
        float lg = ob[bid];
        #pragma unroll
        for (int w2=0;w2<4;++w2) lg += red[(u64)w2*128 + tid];
        g_pool[F_LG + (u64)bid*BSZ + tid] = lg;
      }
    }
    grid_sync();   // b6

    // ---- P7: per-b softmax + nll ----
    if (bid < BSZ){
      float* lgs = red;
      float* rp  = red + 256;
      const int b = bid, v = tid;
      const float lg = g_pool[F_LG + (u64)v*BSZ + b];
      lgs[v] = lg; rp[v] = lg;
      __syncthreads();
      for (int o=128;o;o>>=1){ if (tid<o) rp[tid]=fmaxf(rp[tid],rp[tid+o]); __syncthreads(); }
      const float mx = rp[0];
      __syncthreads();
      rp[tid] = __expf(lg-mx);
      __syncthreads();
      for (int o=128;o;o>>=1){ if (tid<o) rp[tid]+=rp[tid+o]; __syncthreads(); }
      const float lse = mx + __logf(rp[0]);
      dout[((u64)b*TLEN + t)*NTAG + v] = lg;
      if (tid==0){
        const int tag = tag_ids[b*TLEN + t];
        g_pool[F_NLL + (u64)t*BSZ + b] = lse - lgs[tag];
      }
    }
    // no trailing barrier: next-step P1 touches disjoint buffers; b1 orders reuse
  }
  grid_sync();
  // ---- loss ----
  if (bid == 0){
    float* rp = red;
    float ssum = 0.f;
    for (int i=tid; i<TLEN*BSZ; i+=256){
      const int tt = i>>7, b = i&127;
      if (tt < lengths[b]) ssum += g_pool[F_NLL + i];
    }
    rp[tid] = ssum; __syncthreads();
    for (int o=128;o;o>>=1){ if (tid<o) rp[tid]+=rp[tid+o]; __syncthreads(); }
    if (tid==0){
      int den=0;
      for (int b=0;b<BSZ;b++) den += lengths[b];
      dout[(u64)BSZ*TLEN*NTAG] = rp[0]/(float)den;
    }
  }
}

extern "C" void kernel_launch(void* const* d_in, const int* in_sizes, int n_in,
                              void* d_out, int out_size, void* d_ws, size_t ws_size,
                              hipStream_t stream)
{
  const float* enc_embed = (const float*)d_in[0];
  const float* e0_wih = (const float*)d_in[1];
  const float* e0_whh = (const float*)d_in[2];
  const float* e0_bih = (const float*)d_in[3];
  const float* e0_bhh = (const float*)d_in[4];
  const float* e1_wih = (const float*)d_in[5];
  const float* e1_whh = (const float*)d_in[6];
  const float* e1_bih = (const float*)d_in[7];
  const float* e1_bhh = (const float*)d_in[8];
  const float* dec_embed = (const float*)d_in[9];
  const float* d_wih = (const float*)d_in[10];
  const float* d_whh = (const float*)d_in[11];
  const float* d_bih = (const float*)d_in[12];
  const float* d_bhh = (const float*)d_in[13];
  const float* concat_w = (const float*)d_in[14];
  const float* concat_b = (const float*)d_in[15];
  const float* out_w = (const float*)d_in[16];
  const float* out_b = (const float*)d_in[17];
  const int* input_ids = (const int*)d_in[18];
  const int* tag_ids  = (const int*)d_in[19];
  const int* lengths  = (const int*)d_in[20];
  float* dout = (float*)d_out;

  const dim3 gxg(TLEN, G3/64);

  gemm_gx<AM_ENC><<<gxg,256,0,stream>>>(enc_embed,0,0,input_ids,e0_wih,e0_bih,F_GX,HDIM);
  scan_kernel<false,false><<<NBLK,256,0,stream>>>(F_GX, F_T0, F_H0F, e0_whh, e0_bhh, lengths, F_OF0);
  gemm_gx<AM_ENC><<<gxg,256,0,stream>>>(enc_embed,0,0,input_ids,
                                        e0_wih+(u64)G3*HDIM, e0_bih+G3, F_GX, HDIM);
  scan_kernel<true,false><<<NBLK,256,0,stream>>>(F_GX, F_T0, F_H0B,
                                        e0_whh+(u64)G3*HDIM, e0_bhh+G3, lengths, F_OB0);
  gemm_gx<AM_CAT><<<gxg,256,0,stream>>>(nullptr, F_OF0, F_OB0, nullptr,
                                        e1_wih, e1_bih, F_GX, 2*HDIM);
  scan_kernel<false,false><<<NBLK,256,0,stream>>>(F_GX, F_T0, F_T1, e1_whh, e1_bhh, lengths, F_ENC);
  gemm_gx<AM_CAT><<<gxg,256,0,stream>>>(nullptr, F_OF0, F_OB0, nullptr,
                                        e1_wih+(u64)G3*2*HDIM, e1_bih+G3, F_GX, 2*HDIM);
  scan_kernel<true,true><<<NBLK,256,0,stream>>>(F_GX, F_T0, F_T1,
                                        e1_whh+(u64)G3*HDIM, e1_bhh+G3, lengths, F_ENC);
  gemm_gx<AM_DEC><<<gxg,256,0,stream>>>(dec_embed,0,0,tag_ids, d_wih, d_bih, F_GX, HDIM);
  conv_w<<<256,256,0,stream>>>(concat_w, out_w);
  enc_t<<<dim3(TLEN,8),256,0,stream>>>();
  decoder_kernel<<<NBLK,256,0,stream>>>(d_whh, d_bhh,
                                        d_wih+(u64)G3*HDIM, d_bih+G3,
                                        d_whh+(u64)G3*HDIM, d_bhh+G3,
                                        concat_b, out_b,
                                        tag_ids, lengths, dout);
}